// Round 1
// baseline (377.732 us; speedup 1.0000x reference)
//
#include <hip/hip_runtime.h>
#include <math.h>

#define NB 8
#define ND 64
#define NN 65536
#define NC 32
#define NSPLIT 2
constexpr float EPSF = 1e-12f;

// ws layout (floats):
// sums2   [NSPLIT][NB][NC][ND]  off 0        size 32768
// counts  [NB][NC] (int)        off 32768    size 256
// centersT[NB][ND][NC]          off 33024    size 16384
// c2g     [NB][NC]              off 49408    size 256
// wg      [NB][NC]              off 49664    size 256

__global__ __launch_bounds__(256) void k_count(const int* __restrict__ labels,
                                               int* __restrict__ counts,
                                               float* __restrict__ out) {
    const int b = blockIdx.x, tid = threadIdx.x;
    __shared__ int bins[4][NC];
    const int w = tid >> 6;
    if (tid < 4 * NC) ((int*)bins)[tid] = 0;
    if (b == 0 && tid == 0) out[0] = 0.f;  // harness poisons d_out with 0xAA
    __syncthreads();
    const int4* lp = (const int4*)(labels + (size_t)b * NN);
    for (int i = tid; i < NN / 4; i += 256) {
        int4 v = lp[i];
        atomicAdd(&bins[w][v.x & (NC - 1)], 1);
        atomicAdd(&bins[w][v.y & (NC - 1)], 1);
        atomicAdd(&bins[w][v.z & (NC - 1)], 1);
        atomicAdd(&bins[w][v.w & (NC - 1)], 1);
    }
    __syncthreads();
    if (tid < NC)
        counts[b * NC + tid] = bins[0][tid] + bins[1][tid] + bins[2][tid] + bins[3][tid];
}

// Per-(b, d, split) cluster sums. bins[c][lane]: bank = lane%32 -> 2-way max (free).
// atomicAdd (no return ds_add_f32) breaks the read-modify-write dependency chain.
__global__ __launch_bounds__(256) void k_sums(const float* __restrict__ data,
                                              const int* __restrict__ labels,
                                              float* __restrict__ sums2) {
    const int d = blockIdx.x, split = blockIdx.y, b = blockIdx.z;
    const int tid = threadIdx.x, lane = tid & 63;
    __shared__ float bins[NC][64];  // 8 KB
    for (int i = tid; i < NC * 64; i += 256) ((float*)bins)[i] = 0.f;
    __syncthreads();
    const float4* xp = (const float4*)(data + ((size_t)b * ND + d) * NN) + (size_t)split * (NN / 4 / NSPLIT);
    const int4*  lp = (const int4*)(labels + (size_t)b * NN) + (size_t)split * (NN / 4 / NSPLIT);
    for (int i = tid; i < NN / 4 / NSPLIT; i += 256) {
        float4 x = xp[i];
        int4 c = lp[i];
        atomicAdd(&bins[c.x & (NC - 1)][lane], x.x);
        atomicAdd(&bins[c.y & (NC - 1)][lane], x.y);
        atomicAdd(&bins[c.z & (NC - 1)][lane], x.z);
        atomicAdd(&bins[c.w & (NC - 1)][lane], x.w);
    }
    __syncthreads();
    const int c = tid >> 3, j = tid & 7;
    float s = 0.f;
#pragma unroll
    for (int i = 0; i < 8; ++i) s += bins[c][j * 8 + i];
    s += __shfl_xor(s, 1);
    s += __shfl_xor(s, 2);
    s += __shfl_xor(s, 4);
    if (j == 0) sums2[(((size_t)split * NB + b) * NC + c) * ND + d] = s;
}

__global__ __launch_bounds__(256) void k_centers(const float* __restrict__ sums2,
                                                 const int* __restrict__ counts,
                                                 float* __restrict__ centersT,
                                                 float* __restrict__ c2g,
                                                 float* __restrict__ wg,
                                                 float* __restrict__ out) {
    const int b = blockIdx.x, tid = threadIdx.x;
    __shared__ float cent[NC][ND];  // 8 KB
    __shared__ float invs[NC], reals[NC], c2s[NC];
    __shared__ float ncl_s;
    __shared__ float red[4];
    if (tid < NC) {
        int cnt = counts[b * NC + tid];
        reals[tid] = cnt > 0 ? 1.f : 0.f;
        invs[tid]  = cnt > 0 ? 1.f / (float)cnt : 0.f;
    }
    __syncthreads();
    if (tid == 0) {
        float nc = 0.f;
        for (int c = 0; c < NC; ++c) nc += reals[c];
        ncl_s = nc;
    }
    for (int i = tid; i < NC * ND; i += 256) {
        int c = i >> 6, d = i & 63;
        float v = (sums2[((size_t)b * NC + c) * ND + d] +
                   sums2[(((size_t)NB + b) * NC + c) * ND + d]) * invs[c];
        cent[c][d] = v;
        centersT[((size_t)b * ND + d) * NC + c] = v;  // transposed [d][C] for k_var gather
    }
    __syncthreads();
    {
        int c = tid >> 3, j = tid & 7;
        float s = 0.f;
#pragma unroll
        for (int i = 0; i < 8; ++i) { float v = cent[c][j * 8 + i]; s = fmaf(v, v, s); }
        s += __shfl_xor(s, 1);
        s += __shfl_xor(s, 2);
        s += __shfl_xor(s, 4);
        if (j == 0) { c2s[c] = s; c2g[b * NC + c] = s; }
    }
    __syncthreads();
    const float ncl = ncl_s;
    if (tid < NC) wg[b * NC + tid] = invs[tid] / (ncl * (float)NB);
    // dist term: 1024 pairs / 256 threads = 4 each.
    // Reference masking: cost==0 when c==e (eye) or either cluster empty (dummy adds >= 2).
    float acc = 0.f;
#pragma unroll
    for (int k = 0; k < 4; ++k) {
        int p = tid * 4 + k;
        int c = p >> 5, e = p & (NC - 1);
        if (c != e && reals[c] > 0.f && reals[e] > 0.f) {
            float cd = 0.f;
            for (int dd = 0; dd < ND; ++dd) cd = fmaf(cent[c][dd], cent[e][dd], cd);
            float cd2 = fmaxf(c2s[c] + c2s[e] - 2.f * cd, EPSF);
            float m = fmaxf(2.f - sqrtf(cd2), 0.f);
            acc += m * m;
        }
    }
    const float pairs = ncl * (ncl - 1.f) * 0.5f;
    acc = acc / (2.f * pairs * (float)NB);  // linear scale, applied per-thread pre-reduce
    // reg term: delta_reg = sqrt(64) = 8; empty clusters give cnorm=sqrt(EPS) -> 0 contribution
    if (tid < NC) {
        float cn = sqrtf(fmaxf(c2s[tid], EPSF));
        float m = fmaxf(cn - 8.f, 0.f);
        acc += (m * m) / (ncl * (float)NB);
    }
#pragma unroll
    for (int o = 32; o >= 1; o >>= 1) acc += __shfl_xor(acc, o);
    if ((tid & 63) == 0) red[tid >> 6] = acc;
    __syncthreads();
    if (tid == 0) atomicAdd(out, red[0] + red[1] + red[2] + red[3]);
}

// var term: per point, d2 = x2 + c2 - 2*dot (same expanded form + EPS clamp as reference)
__global__ __launch_bounds__(256) void k_var(const float* __restrict__ data,
                                             const int* __restrict__ labels,
                                             const float* __restrict__ centersT,
                                             const float* __restrict__ c2g,
                                             const float* __restrict__ wg,
                                             float* __restrict__ out) {
    const int chunk = blockIdx.x, b = blockIdx.y, tid = threadIdx.x;
    __shared__ float cT[ND][NC];  // [d][c]: gather banks on c -> random labels spread banks
    __shared__ float c2s[NC], ws[NC];
    __shared__ float red[4];
    for (int i = tid; i < ND * NC; i += 256) ((float*)cT)[i] = centersT[(size_t)b * ND * NC + i];
    if (tid < NC) { c2s[tid] = c2g[b * NC + tid]; ws[tid] = wg[b * NC + tid]; }
    __syncthreads();
    const int n0 = chunk * 1024 + tid * 4;
    int4 c4 = *(const int4*)(labels + (size_t)b * NN + n0);
    const int cx = c4.x & 31, cy = c4.y & 31, cz = c4.z & 31, cw = c4.w & 31;
    const float* base = data + (size_t)b * ND * NN + n0;
    float dp0 = 0, dp1 = 0, dp2 = 0, dp3 = 0, q0 = 0, q1 = 0, q2 = 0, q3 = 0;
#pragma unroll 4
    for (int d = 0; d < ND; ++d) {
        float4 x = *(const float4*)(base + (size_t)d * NN);
        dp0 = fmaf(x.x, cT[d][cx], dp0);
        dp1 = fmaf(x.y, cT[d][cy], dp1);
        dp2 = fmaf(x.z, cT[d][cz], dp2);
        dp3 = fmaf(x.w, cT[d][cw], dp3);
        q0 = fmaf(x.x, x.x, q0);
        q1 = fmaf(x.y, x.y, q1);
        q2 = fmaf(x.z, x.z, q2);
        q3 = fmaf(x.w, x.w, q3);
    }
    float t0 = fmaxf(q0 + c2s[cx] - 2.f * dp0, EPSF);
    float t1 = fmaxf(q1 + c2s[cy] - 2.f * dp1, EPSF);
    float t2 = fmaxf(q2 + c2s[cz] - 2.f * dp2, EPSF);
    float t3 = fmaxf(q3 + c2s[cw] - 2.f * dp3, EPSF);
    float e0 = fmaxf(sqrtf(t0) - 1.f, 0.f);
    float e1 = fmaxf(sqrtf(t1) - 1.f, 0.f);
    float e2 = fmaxf(sqrtf(t2) - 1.f, 0.f);
    float e3 = fmaxf(sqrtf(t3) - 1.f, 0.f);
    float acc = e0 * e0 * ws[cx] + e1 * e1 * ws[cy] + e2 * e2 * ws[cz] + e3 * e3 * ws[cw];
#pragma unroll
    for (int o = 32; o >= 1; o >>= 1) acc += __shfl_xor(acc, o);
    if ((tid & 63) == 0) red[tid >> 6] = acc;
    __syncthreads();
    if (tid == 0) atomicAdd(out, red[0] + red[1] + red[2] + red[3]);
}

extern "C" void kernel_launch(void* const* d_in, const int* in_sizes, int n_in,
                              void* d_out, int out_size, void* d_ws, size_t ws_size,
                              hipStream_t stream) {
    const float* data  = (const float*)d_in[0];
    const int* labels  = (const int*)d_in[1];
    float* out = (float*)d_out;
    float* ws  = (float*)d_ws;
    float* sums2    = ws;                    // 32768 floats
    int*   counts   = (int*)(ws + 32768);    // 256 ints
    float* centersT = ws + 33024;            // 16384 floats
    float* c2g      = ws + 49408;            // 256 floats
    float* wg       = ws + 49664;            // 256 floats

    k_count<<<NB, 256, 0, stream>>>(labels, counts, out);
    k_sums<<<dim3(ND, NSPLIT, NB), 256, 0, stream>>>(data, labels, sums2);
    k_centers<<<NB, 256, 0, stream>>>(sums2, counts, centersT, c2g, wg, out);
    k_var<<<dim3(NN / 1024, NB), 256, 0, stream>>>(data, labels, centersT, c2g, wg, out);
}

// Round 2
// 362.828 us; speedup vs baseline: 1.0411x; 1.0411x over previous
//
#include <hip/hip_runtime.h>
#include <math.h>

#define NB 8
#define ND 64
#define NN 65536
#define NC 32
#define NSPLIT 4
constexpr float EPSF = 1e-12f;

// ws layout (floats):
// sums2   [NSPLIT][NB][NC][ND]  off 0      size 65536
// counts  [NB][NC] (int)        off 65536  size 256
// centersT[NB][ND][NC]          off 65792  size 16384
// c2g     [NB][NC]              off 82176  size 256
// wg      [NB][NC]              off 82432  size 256
// cterm   [NB]                  off 82688  size 8
// partials[NB][128]             off 82696  size 1024

// Per-(b, d, split) cluster sums. bins[c][lane]: bank = lane%32 -> 2-way max (free).
// unsafeAtomicAdd -> native ds_add_f32 (no return): fire-and-forget, no dependent
// chain, so the float4 staging loads pipeline freely. d==0 blocks also build the
// label histogram (native int ds_add) -> global counts.
__global__ __launch_bounds__(256) void k_sums(const float* __restrict__ data,
                                              const int* __restrict__ labels,
                                              float* __restrict__ sums2,
                                              int* __restrict__ counts) {
    const int d = blockIdx.x, split = blockIdx.y, b = blockIdx.z;
    const int tid = threadIdx.x, lane = tid & 63;
    __shared__ float bins[NC][64];  // 8 KB
    __shared__ int cnt[NC];
    for (int i = tid; i < NC * 64; i += 256) ((float*)bins)[i] = 0.f;
    const bool do_count = (d == 0);
    if (do_count && tid < NC) cnt[tid] = 0;
    __syncthreads();
    const int Q = NN / NSPLIT / 4;  // 4096 float4s per block
    const float4* xp = (const float4*)(data + ((size_t)b * ND + d) * NN) + (size_t)split * Q;
    const int4*  lp = (const int4*)(labels + (size_t)b * NN) + (size_t)split * Q;
    for (int i = tid; i < Q; i += 512) {  // 2x unroll: two float4/int4 in flight
        float4 x0 = xp[i];
        float4 x1 = xp[i + 256];
        int4 c0 = lp[i];
        int4 c1 = lp[i + 256];
        unsafeAtomicAdd(&bins[c0.x & 31][lane], x0.x);
        unsafeAtomicAdd(&bins[c0.y & 31][lane], x0.y);
        unsafeAtomicAdd(&bins[c0.z & 31][lane], x0.z);
        unsafeAtomicAdd(&bins[c0.w & 31][lane], x0.w);
        unsafeAtomicAdd(&bins[c1.x & 31][lane], x1.x);
        unsafeAtomicAdd(&bins[c1.y & 31][lane], x1.y);
        unsafeAtomicAdd(&bins[c1.z & 31][lane], x1.z);
        unsafeAtomicAdd(&bins[c1.w & 31][lane], x1.w);
        if (do_count) {
            atomicAdd(&cnt[c0.x & 31], 1); atomicAdd(&cnt[c0.y & 31], 1);
            atomicAdd(&cnt[c0.z & 31], 1); atomicAdd(&cnt[c0.w & 31], 1);
            atomicAdd(&cnt[c1.x & 31], 1); atomicAdd(&cnt[c1.y & 31], 1);
            atomicAdd(&cnt[c1.z & 31], 1); atomicAdd(&cnt[c1.w & 31], 1);
        }
    }
    __syncthreads();
    const int c = tid >> 3, j = tid & 7;
    float s = 0.f;
#pragma unroll
    for (int i = 0; i < 8; ++i) s += bins[c][j * 8 + i];
    s += __shfl_xor(s, 1);
    s += __shfl_xor(s, 2);
    s += __shfl_xor(s, 4);
    if (j == 0) sums2[(((size_t)split * NB + b) * NC + c) * ND + d] = s;
    if (do_count && tid < NC) atomicAdd(&counts[b * NC + tid], cnt[tid]);
}

__global__ __launch_bounds__(256) void k_centers(const float* __restrict__ sums2,
                                                 const int* __restrict__ counts,
                                                 float* __restrict__ centersT,
                                                 float* __restrict__ c2g,
                                                 float* __restrict__ wg,
                                                 float* __restrict__ cterm) {
    const int b = blockIdx.x, tid = threadIdx.x;
    __shared__ float cent[NC][ND];  // 8 KB
    __shared__ float invs[NC], reals[NC], c2s[NC];
    __shared__ float ncl_s;
    __shared__ float red[4];
    if (tid < NC) {
        int cntv = counts[b * NC + tid];
        reals[tid] = cntv > 0 ? 1.f : 0.f;
        invs[tid]  = cntv > 0 ? 1.f / (float)cntv : 0.f;
    }
    __syncthreads();
    if (tid == 0) {
        float nc = 0.f;
        for (int c = 0; c < NC; ++c) nc += reals[c];
        ncl_s = nc;
    }
    for (int i = tid; i < NC * ND; i += 256) {
        int c = i >> 6, d = i & 63;
        float v = 0.f;
#pragma unroll
        for (int s = 0; s < NSPLIT; ++s)
            v += sums2[(((size_t)s * NB + b) * NC + c) * ND + d];
        v *= invs[c];
        cent[c][d] = v;
        centersT[((size_t)b * ND + d) * NC + c] = v;  // transposed [d][C] for k_var gather
    }
    __syncthreads();
    {
        int c = tid >> 3, j = tid & 7;
        float s = 0.f;
#pragma unroll
        for (int i = 0; i < 8; ++i) { float v = cent[c][j * 8 + i]; s = fmaf(v, v, s); }
        s += __shfl_xor(s, 1);
        s += __shfl_xor(s, 2);
        s += __shfl_xor(s, 4);
        if (j == 0) { c2s[c] = s; c2g[b * NC + c] = s; }
    }
    __syncthreads();
    const float ncl = ncl_s;
    if (tid < NC) wg[b * NC + tid] = invs[tid] / (ncl * (float)NB);
    // dist term: 1024 pairs / 256 threads = 4 each.
    // Reference masking: cost==0 when c==e (eye) or either cluster empty.
    float acc = 0.f;
#pragma unroll
    for (int k = 0; k < 4; ++k) {
        int p = tid * 4 + k;
        int c = p >> 5, e = p & (NC - 1);
        if (c != e && reals[c] > 0.f && reals[e] > 0.f) {
            float cd = 0.f;
            for (int dd = 0; dd < ND; ++dd) cd = fmaf(cent[c][dd], cent[e][dd], cd);
            float cd2 = fmaxf(c2s[c] + c2s[e] - 2.f * cd, EPSF);
            float m = fmaxf(2.f - sqrtf(cd2), 0.f);
            acc += m * m;
        }
    }
    const float pairs = ncl * (ncl - 1.f) * 0.5f;
    acc = acc / (2.f * pairs * (float)NB);
    // reg term: delta_reg = sqrt(64) = 8
    if (tid < NC) {
        float cn = sqrtf(fmaxf(c2s[tid], EPSF));
        float m = fmaxf(cn - 8.f, 0.f);
        acc += (m * m) / (ncl * (float)NB);
    }
#pragma unroll
    for (int o = 32; o >= 1; o >>= 1) acc += __shfl_xor(acc, o);
    if ((tid & 63) == 0) red[tid >> 6] = acc;
    __syncthreads();
    if (tid == 0) cterm[b] = red[0] + red[1] + red[2] + red[3];
}

// var term: per point, d2 = x2 + c2 - 2*dot (same expanded form + EPS clamp as ref).
// 1024 blocks x 512-pt chunks, float2 loads, partials (no global float atomics).
__global__ __launch_bounds__(256) void k_var(const float* __restrict__ data,
                                             const int* __restrict__ labels,
                                             const float* __restrict__ centersT,
                                             const float* __restrict__ c2g,
                                             const float* __restrict__ wg,
                                             float* __restrict__ partials) {
    const int chunk = blockIdx.x, b = blockIdx.y, tid = threadIdx.x;
    __shared__ float cT[ND][NC];  // [d][c]: gather banks on c -> labels spread banks
    __shared__ float c2s[NC], wsm[NC];
    __shared__ float red[4];
    for (int i = tid; i < ND * NC / 4; i += 256)
        ((float4*)cT)[i] = ((const float4*)(centersT + (size_t)b * ND * NC))[i];
    if (tid < NC) { c2s[tid] = c2g[b * NC + tid]; wsm[tid] = wg[b * NC + tid]; }
    __syncthreads();
    const int n0 = chunk * 512 + tid * 2;
    int2 cv = *(const int2*)(labels + (size_t)b * NN + n0);
    const int cx = cv.x & 31, cy = cv.y & 31;
    const float* base = data + (size_t)b * ND * NN + n0;
    float dp0 = 0, dp1 = 0, q0 = 0, q1 = 0;
#pragma unroll 8
    for (int d = 0; d < ND; ++d) {
        float2 x = *(const float2*)(base + (size_t)d * NN);
        dp0 = fmaf(x.x, cT[d][cx], dp0);
        dp1 = fmaf(x.y, cT[d][cy], dp1);
        q0 = fmaf(x.x, x.x, q0);
        q1 = fmaf(x.y, x.y, q1);
    }
    float t0 = fmaxf(q0 + c2s[cx] - 2.f * dp0, EPSF);
    float t1 = fmaxf(q1 + c2s[cy] - 2.f * dp1, EPSF);
    float e0 = fmaxf(sqrtf(t0) - 1.f, 0.f);
    float e1 = fmaxf(sqrtf(t1) - 1.f, 0.f);
    float acc = e0 * e0 * wsm[cx] + e1 * e1 * wsm[cy];
#pragma unroll
    for (int o = 32; o >= 1; o >>= 1) acc += __shfl_xor(acc, o);
    if ((tid & 63) == 0) red[tid >> 6] = acc;
    __syncthreads();
    if (tid == 0) partials[b * 128 + chunk] = red[0] + red[1] + red[2] + red[3];
}

__global__ __launch_bounds__(256) void k_final(const float* __restrict__ partials,
                                               const float* __restrict__ cterm,
                                               float* __restrict__ out) {
    const int tid = threadIdx.x;
    __shared__ float red[4];
    float s = 0.f;
    for (int i = tid; i < NB * 128; i += 256) s += partials[i];
    if (tid < NB) s += cterm[tid];
#pragma unroll
    for (int o = 32; o >= 1; o >>= 1) s += __shfl_xor(s, o);
    if ((tid & 63) == 0) red[tid >> 6] = s;
    __syncthreads();
    if (tid == 0) out[0] = red[0] + red[1] + red[2] + red[3];
}

extern "C" void kernel_launch(void* const* d_in, const int* in_sizes, int n_in,
                              void* d_out, int out_size, void* d_ws, size_t ws_size,
                              hipStream_t stream) {
    const float* data  = (const float*)d_in[0];
    const int* labels  = (const int*)d_in[1];
    float* out = (float*)d_out;
    float* ws  = (float*)d_ws;
    float* sums2    = ws;                    // 65536 floats
    int*   counts   = (int*)(ws + 65536);    // 256 ints
    float* centersT = ws + 65792;            // 16384 floats
    float* c2g      = ws + 82176;            // 256 floats
    float* wg       = ws + 82432;            // 256 floats
    float* cterm    = ws + 82688;            // 8 floats
    float* partials = ws + 82696;            // 1024 floats

    hipMemsetAsync(counts, 0, NB * NC * sizeof(int), stream);
    k_sums<<<dim3(ND, NSPLIT, NB), 256, 0, stream>>>(data, labels, sums2, counts);
    k_centers<<<NB, 256, 0, stream>>>(sums2, counts, centersT, c2g, wg, cterm);
    k_var<<<dim3(128, NB), 256, 0, stream>>>(data, labels, centersT, c2g, wg, partials);
    k_final<<<1, 256, 0, stream>>>(partials, cterm, out);
}

// Round 3
// 236.029 us; speedup vs baseline: 1.6004x; 1.5372x over previous
//
#include <hip/hip_runtime.h>
#include <math.h>

#define NB 8
#define ND 64
#define NN 65536
#define NC 32
#define NSPLIT 2
constexpr float EPSF = 1e-12f;

// ws layout (floats):
// sums2   [NSPLIT][NB][NC][ND] @0      (32768)
// countsf [NSPLIT][NB][NC]     @32768  (512)
// centersT[NB][ND][NC]         @33280  (16384)
// c2g     [NB][NC]             @49664  (256)
// wg      [NB][NC]             @49920  (256)
// cterm   [NB]                 @50176  (8)
// partials[NB][128]            @50184  (1024)

// Per-(b, d, split) cluster sums with ZERO atomics: each thread owns a private
// LDS column bins[*][tid] (bank = tid%32 -> 2-way, free). Plain RMW ds ops.
// Grid x-dim has ND+1 slices: slice d==ND accumulates 1.0f per point -> counts
// (exact in fp32), reusing the same code path.
__global__ __launch_bounds__(256) void k_sums(const float* __restrict__ data,
                                              const int* __restrict__ labels,
                                              float* __restrict__ sums2,
                                              float* __restrict__ countsf) {
    const int d = blockIdx.x, split = blockIdx.y, b = blockIdx.z;
    const int tid = threadIdx.x;
    __shared__ float bins[NC][256];  // 32 KB
    for (int i = tid; i < NC * 256 / 4; i += 256)
        ((float4*)bins)[i] = float4{0.f, 0.f, 0.f, 0.f};
    __syncthreads();
    const int Q = NN / NSPLIT / 4;  // 8192 int4/float4 per (b,split)
    const int4* lp = (const int4*)(labels + (size_t)b * NN) + (size_t)split * Q;
    if (d == ND) {  // count slice
        for (int i = tid; i < Q; i += 512) {
            int4 c0 = lp[i];
            int4 c1 = lp[i + 256];
            bins[c0.x & 31][tid] += 1.f;
            bins[c0.y & 31][tid] += 1.f;
            bins[c0.z & 31][tid] += 1.f;
            bins[c0.w & 31][tid] += 1.f;
            bins[c1.x & 31][tid] += 1.f;
            bins[c1.y & 31][tid] += 1.f;
            bins[c1.z & 31][tid] += 1.f;
            bins[c1.w & 31][tid] += 1.f;
        }
    } else {
        const float4* xp = (const float4*)(data + ((size_t)b * ND + d) * NN) + (size_t)split * Q;
        for (int i = tid; i < Q; i += 512) {  // 2 float4 + 2 int4 in flight
            float4 x0 = xp[i];
            float4 x1 = xp[i + 256];
            int4 c0 = lp[i];
            int4 c1 = lp[i + 256];
            bins[c0.x & 31][tid] += x0.x;
            bins[c0.y & 31][tid] += x0.y;
            bins[c0.z & 31][tid] += x0.z;
            bins[c0.w & 31][tid] += x0.w;
            bins[c1.x & 31][tid] += x1.x;
            bins[c1.y & 31][tid] += x1.y;
            bins[c1.z & 31][tid] += x1.z;
            bins[c1.w & 31][tid] += x1.w;
        }
    }
    __syncthreads();
    // column reduce: thread (c=tid>>3, j=tid&7) sums bins[c][i*8+j] (8-bank spread)
    const int c = tid >> 3, j = tid & 7;
    float s = 0.f;
#pragma unroll
    for (int i = 0; i < 32; ++i) s += bins[c][i * 8 + j];
    s += __shfl_xor(s, 1);
    s += __shfl_xor(s, 2);
    s += __shfl_xor(s, 4);
    if (j == 0) {
        if (d == ND) countsf[((size_t)split * NB + b) * NC + c] = s;
        else sums2[(((size_t)split * NB + b) * NC + c) * ND + d] = s;
    }
}

__global__ __launch_bounds__(256) void k_centers(const float* __restrict__ sums2,
                                                 const float* __restrict__ countsf,
                                                 float* __restrict__ centersT,
                                                 float* __restrict__ c2g,
                                                 float* __restrict__ wg,
                                                 float* __restrict__ cterm) {
    const int b = blockIdx.x, tid = threadIdx.x;
    __shared__ float cent[NC][ND];  // 8 KB
    __shared__ float invs[NC], reals[NC], c2s[NC];
    __shared__ float ncl_s;
    __shared__ float red[4];
    if (tid < NC) {
        float cntv = 0.f;
#pragma unroll
        for (int s = 0; s < NSPLIT; ++s) cntv += countsf[((size_t)s * NB + b) * NC + tid];
        reals[tid] = cntv > 0.f ? 1.f : 0.f;
        invs[tid]  = cntv > 0.f ? 1.f / cntv : 0.f;
    }
    __syncthreads();
    if (tid == 0) {
        float nc = 0.f;
        for (int c = 0; c < NC; ++c) nc += reals[c];
        ncl_s = nc;
    }
    for (int i = tid; i < NC * ND; i += 256) {
        int c = i >> 6, d = i & 63;
        float v = 0.f;
#pragma unroll
        for (int s = 0; s < NSPLIT; ++s)
            v += sums2[(((size_t)s * NB + b) * NC + c) * ND + d];
        v *= invs[c];
        cent[c][d] = v;
        centersT[((size_t)b * ND + d) * NC + c] = v;  // [d][C] for k_var gather
    }
    __syncthreads();
    {
        int c = tid >> 3, j = tid & 7;
        float s = 0.f;
#pragma unroll
        for (int i = 0; i < 8; ++i) { float v = cent[c][j * 8 + i]; s = fmaf(v, v, s); }
        s += __shfl_xor(s, 1);
        s += __shfl_xor(s, 2);
        s += __shfl_xor(s, 4);
        if (j == 0) { c2s[c] = s; c2g[b * NC + c] = s; }
    }
    __syncthreads();
    const float ncl = ncl_s;
    if (tid < NC) wg[b * NC + tid] = invs[tid] / (ncl * (float)NB);
    // dist term: 1024 pairs / 256 threads = 4 each; zero when c==e or either empty.
    float acc = 0.f;
#pragma unroll
    for (int k = 0; k < 4; ++k) {
        int p = tid * 4 + k;
        int c = p >> 5, e = p & (NC - 1);
        if (c != e && reals[c] > 0.f && reals[e] > 0.f) {
            float cd = 0.f;
            for (int dd = 0; dd < ND; ++dd) cd = fmaf(cent[c][dd], cent[e][dd], cd);
            float cd2 = fmaxf(c2s[c] + c2s[e] - 2.f * cd, EPSF);
            float m = fmaxf(2.f - sqrtf(cd2), 0.f);
            acc += m * m;
        }
    }
    const float pairs = ncl * (ncl - 1.f) * 0.5f;
    acc = acc / (2.f * pairs * (float)NB);
    // reg term: delta_reg = sqrt(64) = 8
    if (tid < NC) {
        float cn = sqrtf(fmaxf(c2s[tid], EPSF));
        float m = fmaxf(cn - 8.f, 0.f);
        acc += (m * m) / (ncl * (float)NB);
    }
#pragma unroll
    for (int o = 32; o >= 1; o >>= 1) acc += __shfl_xor(acc, o);
    if ((tid & 63) == 0) red[tid >> 6] = acc;
    __syncthreads();
    if (tid == 0) cterm[b] = red[0] + red[1] + red[2] + red[3];
}

// var term: per point, d2 = x2 + c2 - 2*dot (same expanded form + EPS clamp as ref).
__global__ __launch_bounds__(256) void k_var(const float* __restrict__ data,
                                             const int* __restrict__ labels,
                                             const float* __restrict__ centersT,
                                             const float* __restrict__ c2g,
                                             const float* __restrict__ wg,
                                             float* __restrict__ partials) {
    const int chunk = blockIdx.x, b = blockIdx.y, tid = threadIdx.x;
    __shared__ float cT[ND][NC];  // [d][c]: gather banks on c
    __shared__ float c2s[NC], wsm[NC];
    __shared__ float red[4];
    const int n0 = chunk * 512 + tid * 2;
    int2 cv = *(const int2*)(labels + (size_t)b * NN + n0);  // issue label load first
    for (int i = tid; i < ND * NC / 4; i += 256)
        ((float4*)cT)[i] = ((const float4*)(centersT + (size_t)b * ND * NC))[i];
    if (tid < NC) { c2s[tid] = c2g[b * NC + tid]; wsm[tid] = wg[b * NC + tid]; }
    __syncthreads();
    const int cx = cv.x & 31, cy = cv.y & 31;
    const float* base = data + (size_t)b * ND * NN + n0;
    float dp0 = 0, dp1 = 0, q0 = 0, q1 = 0;
#pragma unroll 8
    for (int d = 0; d < ND; ++d) {
        float2 x = *(const float2*)(base + (size_t)d * NN);
        dp0 = fmaf(x.x, cT[d][cx], dp0);
        dp1 = fmaf(x.y, cT[d][cy], dp1);
        q0 = fmaf(x.x, x.x, q0);
        q1 = fmaf(x.y, x.y, q1);
    }
    float t0 = fmaxf(q0 + c2s[cx] - 2.f * dp0, EPSF);
    float t1 = fmaxf(q1 + c2s[cy] - 2.f * dp1, EPSF);
    float e0 = fmaxf(sqrtf(t0) - 1.f, 0.f);
    float e1 = fmaxf(sqrtf(t1) - 1.f, 0.f);
    float acc = e0 * e0 * wsm[cx] + e1 * e1 * wsm[cy];
#pragma unroll
    for (int o = 32; o >= 1; o >>= 1) acc += __shfl_xor(acc, o);
    if ((tid & 63) == 0) red[tid >> 6] = acc;
    __syncthreads();
    if (tid == 0) partials[b * 128 + chunk] = red[0] + red[1] + red[2] + red[3];
}

__global__ __launch_bounds__(256) void k_final(const float* __restrict__ partials,
                                               const float* __restrict__ cterm,
                                               float* __restrict__ out) {
    const int tid = threadIdx.x;
    __shared__ float red[4];
    float s = 0.f;
    for (int i = tid; i < NB * 128; i += 256) s += partials[i];
    if (tid < NB) s += cterm[tid];
#pragma unroll
    for (int o = 32; o >= 1; o >>= 1) s += __shfl_xor(s, o);
    if ((tid & 63) == 0) red[tid >> 6] = s;
    __syncthreads();
    if (tid == 0) out[0] = red[0] + red[1] + red[2] + red[3];
}

extern "C" void kernel_launch(void* const* d_in, const int* in_sizes, int n_in,
                              void* d_out, int out_size, void* d_ws, size_t ws_size,
                              hipStream_t stream) {
    const float* data  = (const float*)d_in[0];
    const int* labels  = (const int*)d_in[1];
    float* out = (float*)d_out;
    float* ws  = (float*)d_ws;
    float* sums2    = ws;           // 32768 floats
    float* countsf  = ws + 32768;   // 512 floats
    float* centersT = ws + 33280;   // 16384 floats
    float* c2g      = ws + 49664;   // 256 floats
    float* wg       = ws + 49920;   // 256 floats
    float* cterm    = ws + 50176;   // 8 floats
    float* partials = ws + 50184;   // 1024 floats

    k_sums<<<dim3(ND + 1, NSPLIT, NB), 256, 0, stream>>>(data, labels, sums2, countsf);
    k_centers<<<NB, 256, 0, stream>>>(sums2, countsf, centersT, c2g, wg, cterm);
    k_var<<<dim3(128, NB), 256, 0, stream>>>(data, labels, centersT, c2g, wg, partials);
    k_final<<<1, 256, 0, stream>>>(partials, cterm, out);
}

// Round 4
// 232.712 us; speedup vs baseline: 1.6232x; 1.0143x over previous
//
#include <hip/hip_runtime.h>
#include <math.h>

#define NB 8
#define ND 64
#define NN 65536
#define NC 32
#define NSPLIT 2
constexpr float EPSF = 1e-12f;

// ws layout (floats):
// sums2    [NSPLIT][NB][NC][ND] @0      (32768)
// countsf  [NSPLIT][NB][NC]     @32768  (512)
// centersT2[NB][32][NC*2]       @33280  (16384)  // float2-packed: (d2,c) -> {c[2d2],c[2d2+1]}
// c2g      [NB][NC]             @49664  (256)
// wg       [NB][NC]             @49920  (256)
// cterm    [NB]                 @50176  (8)
// partials [NB][64]             @50184  (512)

// Per-(b, d, split) cluster sums, zero atomics: each thread owns private LDS
// column bins[*][tid] (bank = tid%32 -> 2-way, free). 4x unrolled loads.
// Slice d==ND accumulates 1.0f -> counts (exact in fp32).
__global__ __launch_bounds__(256) void k_sums(const float* __restrict__ data,
                                              const int* __restrict__ labels,
                                              float* __restrict__ sums2,
                                              float* __restrict__ countsf) {
    const int d = blockIdx.x, split = blockIdx.y, b = blockIdx.z;
    const int tid = threadIdx.x;
    __shared__ float bins[NC][256];  // 32 KB
    for (int i = tid; i < NC * 256 / 4; i += 256)
        ((float4*)bins)[i] = float4{0.f, 0.f, 0.f, 0.f};
    __syncthreads();
    const int Q = NN / NSPLIT / 4;  // 8192 float4/int4 per (b,split)
    const int4* lp = (const int4*)(labels + (size_t)b * NN) + (size_t)split * Q;
    if (d == ND) {  // count slice
        for (int i = tid; i < Q; i += 1024) {
            int4 c0 = lp[i], c1 = lp[i + 256], c2 = lp[i + 512], c3 = lp[i + 768];
            bins[c0.x & 31][tid] += 1.f; bins[c0.y & 31][tid] += 1.f;
            bins[c0.z & 31][tid] += 1.f; bins[c0.w & 31][tid] += 1.f;
            bins[c1.x & 31][tid] += 1.f; bins[c1.y & 31][tid] += 1.f;
            bins[c1.z & 31][tid] += 1.f; bins[c1.w & 31][tid] += 1.f;
            bins[c2.x & 31][tid] += 1.f; bins[c2.y & 31][tid] += 1.f;
            bins[c2.z & 31][tid] += 1.f; bins[c2.w & 31][tid] += 1.f;
            bins[c3.x & 31][tid] += 1.f; bins[c3.y & 31][tid] += 1.f;
            bins[c3.z & 31][tid] += 1.f; bins[c3.w & 31][tid] += 1.f;
        }
    } else {
        const float4* xp = (const float4*)(data + ((size_t)b * ND + d) * NN) + (size_t)split * Q;
        for (int i = tid; i < Q; i += 1024) {  // 4 float4 + 4 int4 in flight
            float4 x0 = xp[i], x1 = xp[i + 256], x2 = xp[i + 512], x3 = xp[i + 768];
            int4 c0 = lp[i], c1 = lp[i + 256], c2 = lp[i + 512], c3 = lp[i + 768];
            bins[c0.x & 31][tid] += x0.x; bins[c0.y & 31][tid] += x0.y;
            bins[c0.z & 31][tid] += x0.z; bins[c0.w & 31][tid] += x0.w;
            bins[c1.x & 31][tid] += x1.x; bins[c1.y & 31][tid] += x1.y;
            bins[c1.z & 31][tid] += x1.z; bins[c1.w & 31][tid] += x1.w;
            bins[c2.x & 31][tid] += x2.x; bins[c2.y & 31][tid] += x2.y;
            bins[c2.z & 31][tid] += x2.z; bins[c2.w & 31][tid] += x2.w;
            bins[c3.x & 31][tid] += x3.x; bins[c3.y & 31][tid] += x3.y;
            bins[c3.z & 31][tid] += x3.z; bins[c3.w & 31][tid] += x3.w;
        }
    }
    __syncthreads();
    // column reduce: thread (c=tid>>3, j=tid&7) sums bins[c][i*8+j]
    const int c = tid >> 3, j = tid & 7;
    float s = 0.f;
#pragma unroll
    for (int i = 0; i < 32; ++i) s += bins[c][i * 8 + j];
    s += __shfl_xor(s, 1);
    s += __shfl_xor(s, 2);
    s += __shfl_xor(s, 4);
    if (j == 0) {
        if (d == ND) countsf[((size_t)split * NB + b) * NC + c] = s;
        else sums2[(((size_t)split * NB + b) * NC + c) * ND + d] = s;
    }
}

__global__ __launch_bounds__(256) void k_centers(const float* __restrict__ sums2,
                                                 const float* __restrict__ countsf,
                                                 float* __restrict__ centersT2,
                                                 float* __restrict__ c2g,
                                                 float* __restrict__ wg,
                                                 float* __restrict__ cterm) {
    const int b = blockIdx.x, tid = threadIdx.x;
    __shared__ float cent[NC][ND];  // 8 KB
    __shared__ float invs[NC], reals[NC], c2s[NC];
    __shared__ float ncl_s;
    __shared__ float red[4];
    if (tid < NC) {
        float cntv = 0.f;
#pragma unroll
        for (int s = 0; s < NSPLIT; ++s) cntv += countsf[((size_t)s * NB + b) * NC + tid];
        reals[tid] = cntv > 0.f ? 1.f : 0.f;
        invs[tid]  = cntv > 0.f ? 1.f / cntv : 0.f;
    }
    __syncthreads();
    if (tid == 0) {
        float nc = 0.f;
        for (int c = 0; c < NC; ++c) nc += reals[c];
        ncl_s = nc;
    }
    for (int i = tid; i < NC * ND; i += 256) {
        int c = i >> 6, d = i & 63;
        float v = 0.f;
#pragma unroll
        for (int s = 0; s < NSPLIT; ++s)
            v += sums2[(((size_t)s * NB + b) * NC + c) * ND + d];
        v *= invs[c];
        cent[c][d] = v;
        // float2-packed transpose: [b][d>>1][c*2 + (d&1)]
        centersT2[(size_t)b * 2048 + (size_t)(d >> 1) * 64 + c * 2 + (d & 1)] = v;
    }
    __syncthreads();
    {
        int c = tid >> 3, j = tid & 7;
        float s = 0.f;
#pragma unroll
        for (int i = 0; i < 8; ++i) { float v = cent[c][j * 8 + i]; s = fmaf(v, v, s); }
        s += __shfl_xor(s, 1);
        s += __shfl_xor(s, 2);
        s += __shfl_xor(s, 4);
        if (j == 0) { c2s[c] = s; c2g[b * NC + c] = s; }
    }
    __syncthreads();
    const float ncl = ncl_s;
    if (tid < NC) wg[b * NC + tid] = invs[tid] / (ncl * (float)NB);
    // dist term: 1024 pairs / 256 threads = 4 each; zero when c==e or either empty.
    float acc = 0.f;
#pragma unroll
    for (int k = 0; k < 4; ++k) {
        int p = tid * 4 + k;
        int c = p >> 5, e = p & (NC - 1);
        if (c != e && reals[c] > 0.f && reals[e] > 0.f) {
            float cd = 0.f;
            for (int dd = 0; dd < ND; ++dd) cd = fmaf(cent[c][dd], cent[e][dd], cd);
            float cd2 = fmaxf(c2s[c] + c2s[e] - 2.f * cd, EPSF);
            float m = fmaxf(2.f - sqrtf(cd2), 0.f);
            acc += m * m;
        }
    }
    const float pairs = ncl * (ncl - 1.f) * 0.5f;
    acc = acc / (2.f * pairs * (float)NB);
    // reg term: delta_reg = sqrt(64) = 8
    if (tid < NC) {
        float cn = sqrtf(fmaxf(c2s[tid], EPSF));
        float m = fmaxf(cn - 8.f, 0.f);
        acc += (m * m) / (ncl * (float)NB);
    }
#pragma unroll
    for (int o = 32; o >= 1; o >>= 1) acc += __shfl_xor(acc, o);
    if ((tid & 63) == 0) red[tid >> 6] = acc;
    __syncthreads();
    if (tid == 0) cterm[b] = red[0] + red[1] + red[2] + red[3];
}

// var term: per point, d2 = x2 + c2 - 2*dot (same expanded form + EPS clamp as ref).
// 4 points/thread (float4 loads, 256B in flight at unroll 8); centers float2-packed
// in LDS: gather banks {2c,2c+1} -> <=2-way (free), b64 reads.
__global__ __launch_bounds__(256) void k_var(const float* __restrict__ data,
                                             const int* __restrict__ labels,
                                             const float* __restrict__ centersT2,
                                             const float* __restrict__ c2g,
                                             const float* __restrict__ wg,
                                             float* __restrict__ partials) {
    const int chunk = blockIdx.x, b = blockIdx.y, tid = threadIdx.x;
    __shared__ float2 cT2[32][NC];  // 8 KB: (d2, c) -> {center[2d2][c], center[2d2+1][c]}
    __shared__ float c2s[NC], wsm[NC];
    __shared__ float red[4];
    const int n0 = chunk * 1024 + tid * 4;
    int4 cv = *(const int4*)(labels + (size_t)b * NN + n0);  // issue first
    for (int i = tid; i < 512; i += 256)
        ((float4*)cT2)[i] = ((const float4*)(centersT2 + (size_t)b * 2048))[i];
    if (tid < NC) { c2s[tid] = c2g[b * NC + tid]; wsm[tid] = wg[b * NC + tid]; }
    __syncthreads();
    const int cx = cv.x & 31, cy = cv.y & 31, cz = cv.z & 31, cw = cv.w & 31;
    const float* base = data + (size_t)b * ND * NN + n0;
    float dp0 = 0, dp1 = 0, dp2 = 0, dp3 = 0, q0 = 0, q1 = 0, q2 = 0, q3 = 0;
#pragma unroll 8
    for (int d2 = 0; d2 < 32; ++d2) {
        float4 xa = *(const float4*)(base + (size_t)(2 * d2) * NN);
        float4 xb = *(const float4*)(base + (size_t)(2 * d2 + 1) * NN);
        float2 ca = cT2[d2][cx], cb = cT2[d2][cy], cc = cT2[d2][cz], cd = cT2[d2][cw];
        dp0 = fmaf(xa.x, ca.x, dp0); dp0 = fmaf(xb.x, ca.y, dp0);
        dp1 = fmaf(xa.y, cb.x, dp1); dp1 = fmaf(xb.y, cb.y, dp1);
        dp2 = fmaf(xa.z, cc.x, dp2); dp2 = fmaf(xb.z, cc.y, dp2);
        dp3 = fmaf(xa.w, cd.x, dp3); dp3 = fmaf(xb.w, cd.y, dp3);
        q0 = fmaf(xa.x, xa.x, q0); q0 = fmaf(xb.x, xb.x, q0);
        q1 = fmaf(xa.y, xa.y, q1); q1 = fmaf(xb.y, xb.y, q1);
        q2 = fmaf(xa.z, xa.z, q2); q2 = fmaf(xb.z, xb.z, q2);
        q3 = fmaf(xa.w, xa.w, q3); q3 = fmaf(xb.w, xb.w, q3);
    }
    float t0 = fmaxf(q0 + c2s[cx] - 2.f * dp0, EPSF);
    float t1 = fmaxf(q1 + c2s[cy] - 2.f * dp1, EPSF);
    float t2 = fmaxf(q2 + c2s[cz] - 2.f * dp2, EPSF);
    float t3 = fmaxf(q3 + c2s[cw] - 2.f * dp3, EPSF);
    float e0 = fmaxf(sqrtf(t0) - 1.f, 0.f);
    float e1 = fmaxf(sqrtf(t1) - 1.f, 0.f);
    float e2 = fmaxf(sqrtf(t2) - 1.f, 0.f);
    float e3 = fmaxf(sqrtf(t3) - 1.f, 0.f);
    float acc = e0 * e0 * wsm[cx] + e1 * e1 * wsm[cy] + e2 * e2 * wsm[cz] + e3 * e3 * wsm[cw];
#pragma unroll
    for (int o = 32; o >= 1; o >>= 1) acc += __shfl_xor(acc, o);
    if ((tid & 63) == 0) red[tid >> 6] = acc;
    __syncthreads();
    if (tid == 0) partials[b * 64 + chunk] = red[0] + red[1] + red[2] + red[3];
}

__global__ __launch_bounds__(256) void k_final(const float* __restrict__ partials,
                                               const float* __restrict__ cterm,
                                               float* __restrict__ out) {
    const int tid = threadIdx.x;
    __shared__ float red[4];
    float s = 0.f;
    for (int i = tid; i < NB * 64; i += 256) s += partials[i];
    if (tid < NB) s += cterm[tid];
#pragma unroll
    for (int o = 32; o >= 1; o >>= 1) s += __shfl_xor(s, o);
    if ((tid & 63) == 0) red[tid >> 6] = s;
    __syncthreads();
    if (tid == 0) out[0] = red[0] + red[1] + red[2] + red[3];
}

extern "C" void kernel_launch(void* const* d_in, const int* in_sizes, int n_in,
                              void* d_out, int out_size, void* d_ws, size_t ws_size,
                              hipStream_t stream) {
    const float* data  = (const float*)d_in[0];
    const int* labels  = (const int*)d_in[1];
    float* out = (float*)d_out;
    float* ws  = (float*)d_ws;
    float* sums2     = ws;           // 32768 floats
    float* countsf   = ws + 32768;   // 512 floats
    float* centersT2 = ws + 33280;   // 16384 floats
    float* c2g       = ws + 49664;   // 256 floats
    float* wg        = ws + 49920;   // 256 floats
    float* cterm     = ws + 50176;   // 8 floats
    float* partials  = ws + 50184;   // 512 floats

    k_sums<<<dim3(ND + 1, NSPLIT, NB), 256, 0, stream>>>(data, labels, sums2, countsf);
    k_centers<<<NB, 256, 0, stream>>>(sums2, countsf, centersT2, c2g, wg, cterm);
    k_var<<<dim3(NN / 1024, NB), 256, 0, stream>>>(data, labels, centersT2, c2g, wg, partials);
    k_final<<<1, 256, 0, stream>>>(partials, cterm, out);
}

// Round 5
// 221.714 us; speedup vs baseline: 1.7037x; 1.0496x over previous
//
#include <hip/hip_runtime.h>
#include <math.h>

#define NB 8
#define ND 64
#define NN 65536
#define NC 32
#define NSPLIT 2
constexpr float EPSF = 1e-12f;

// ws layout (floats):
// sums2   [NSPLIT][NB][NC][ND] @0      (32768)
// countsf [NSPLIT][NB][NC]     @32768  (512)

// Per-(b, d, split) cluster sums, zero atomics: each thread owns private LDS
// column bins[*][tid] (bank = tid%32 -> 2-way, free). Iteration-level prefetch:
// next 8 global loads are issued BEFORE the current 16 LDS RMWs, so HBM latency
// hides under the DS block instead of a per-iter vmcnt(0) stall.
// Slice d==ND accumulates 1.0f -> counts (exact in fp32); it also zeroes out[0].
__global__ __launch_bounds__(256) void k_sums(const float* __restrict__ data,
                                              const int* __restrict__ labels,
                                              float* __restrict__ sums2,
                                              float* __restrict__ countsf,
                                              float* __restrict__ out) {
    const int d = blockIdx.x, split = blockIdx.y, b = blockIdx.z;
    const int tid = threadIdx.x;
    __shared__ float bins[NC][256];  // 32 KB
    for (int i = tid; i < NC * 256 / 4; i += 256)
        ((float4*)bins)[i] = float4{0.f, 0.f, 0.f, 0.f};
    if (d == ND && split == 0 && b == 0 && tid == 0) out[0] = 0.f;  // harness poisons d_out
    __syncthreads();
    const int Q = NN / NSPLIT / 4;  // 8192 float4/int4 per (b,split)
    const int4* lp = (const int4*)(labels + (size_t)b * NN) + (size_t)split * Q;
    if (d == ND) {  // count slice (labels only, ~2MB: cheap)
        for (int i = tid; i < Q; i += 1024) {
            int4 c0 = lp[i], c1 = lp[i + 256], c2 = lp[i + 512], c3 = lp[i + 768];
            bins[c0.x & 31][tid] += 1.f; bins[c0.y & 31][tid] += 1.f;
            bins[c0.z & 31][tid] += 1.f; bins[c0.w & 31][tid] += 1.f;
            bins[c1.x & 31][tid] += 1.f; bins[c1.y & 31][tid] += 1.f;
            bins[c1.z & 31][tid] += 1.f; bins[c1.w & 31][tid] += 1.f;
            bins[c2.x & 31][tid] += 1.f; bins[c2.y & 31][tid] += 1.f;
            bins[c2.z & 31][tid] += 1.f; bins[c2.w & 31][tid] += 1.f;
            bins[c3.x & 31][tid] += 1.f; bins[c3.y & 31][tid] += 1.f;
            bins[c3.z & 31][tid] += 1.f; bins[c3.w & 31][tid] += 1.f;
        }
    } else {
        const float4* xp = (const float4*)(data + ((size_t)b * ND + d) * NN) + (size_t)split * Q;
        float4 x0 = xp[tid], x1 = xp[tid + 256], x2 = xp[tid + 512], x3 = xp[tid + 768];
        int4  c0 = lp[tid], c1 = lp[tid + 256], c2 = lp[tid + 512], c3 = lp[tid + 768];
        for (int i = tid;;) {
            const int nxt = i + 1024;
            const bool more = (nxt < Q);
            float4 y0, y1, y2, y3;
            int4 e0, e1, e2, e3;
            if (more) {  // issue next-iter loads BEFORE the DS block
                y0 = xp[nxt]; y1 = xp[nxt + 256]; y2 = xp[nxt + 512]; y3 = xp[nxt + 768];
                e0 = lp[nxt]; e1 = lp[nxt + 256]; e2 = lp[nxt + 512]; e3 = lp[nxt + 768];
            }
            bins[c0.x & 31][tid] += x0.x; bins[c0.y & 31][tid] += x0.y;
            bins[c0.z & 31][tid] += x0.z; bins[c0.w & 31][tid] += x0.w;
            bins[c1.x & 31][tid] += x1.x; bins[c1.y & 31][tid] += x1.y;
            bins[c1.z & 31][tid] += x1.z; bins[c1.w & 31][tid] += x1.w;
            bins[c2.x & 31][tid] += x2.x; bins[c2.y & 31][tid] += x2.y;
            bins[c2.z & 31][tid] += x2.z; bins[c2.w & 31][tid] += x2.w;
            bins[c3.x & 31][tid] += x3.x; bins[c3.y & 31][tid] += x3.y;
            bins[c3.z & 31][tid] += x3.z; bins[c3.w & 31][tid] += x3.w;
            if (!more) break;
            x0 = y0; x1 = y1; x2 = y2; x3 = y3;
            c0 = e0; c1 = e1; c2 = e2; c3 = e3;
            i = nxt;
        }
    }
    __syncthreads();
    // column reduce: thread (c=tid>>3, j=tid&7) sums bins[c][i*8+j]
    const int c = tid >> 3, j = tid & 7;
    float s = 0.f;
#pragma unroll
    for (int i = 0; i < 32; ++i) s += bins[c][i * 8 + j];
    s += __shfl_xor(s, 1);
    s += __shfl_xor(s, 2);
    s += __shfl_xor(s, 4);
    if (j == 0) {
        if (d == ND) countsf[((size_t)split * NB + b) * NC + c] = s;
        else sums2[(((size_t)split * NB + b) * NC + c) * ND + d] = s;
    }
}

// Fused: every block redundantly builds centers (16KB L2-resident sums2 read),
// c2, weights in LDS; chunk-0 blocks also compute dist+reg terms; all blocks
// accumulate their var partial into out via native global f32 atomic add.
__global__ __launch_bounds__(256) void k_var(const float* __restrict__ data,
                                             const int* __restrict__ labels,
                                             const float* __restrict__ sums2,
                                             const float* __restrict__ countsf,
                                             float* __restrict__ out) {
    const int chunk = blockIdx.x, b = blockIdx.y, tid = threadIdx.x;
    __shared__ float2 cT2[32][NC];  // 8 KB: (d2,c) -> {center[2d2][c], center[2d2+1][c]}
    __shared__ float c2s[NC], wsm[NC], invs[NC], reals[NC];
    __shared__ float ncl_s;
    __shared__ float red[4], red2[4];
    const int n0 = chunk * 1024 + tid * 4;
    int4 cv = *(const int4*)(labels + (size_t)b * NN + n0);  // issue early
    if (tid < NC) {
        float cnt = countsf[b * NC + tid] + countsf[(NB + b) * NC + tid];
        reals[tid] = cnt > 0.f ? 1.f : 0.f;
        invs[tid]  = cnt > 0.f ? 1.f / cnt : 0.f;
    }
    __syncthreads();
    if (tid == 0) {
        float nc = 0.f;
        for (int c = 0; c < NC; ++c) nc += reals[c];
        ncl_s = nc;
    }
    for (int i = tid; i < NC * ND; i += 256) {
        int c = i >> 6, d = i & 63;
        float v = (sums2[((size_t)b * NC + c) * ND + d] +
                   sums2[((size_t)(NB + b) * NC + c) * ND + d]) * invs[c];
        ((float*)cT2)[(d >> 1) * 64 + c * 2 + (d & 1)] = v;  // float2-packed transpose
    }
    __syncthreads();
    {
        int c = tid >> 3, j = tid & 7;
        float s = 0.f;
#pragma unroll
        for (int i = 0; i < 8; ++i) {
            int d = j * 8 + i;
            float v = ((float*)cT2)[(d >> 1) * 64 + c * 2 + (d & 1)];
            s = fmaf(v, v, s);
        }
        s += __shfl_xor(s, 1);
        s += __shfl_xor(s, 2);
        s += __shfl_xor(s, 4);
        if (j == 0) c2s[c] = s;
    }
    __syncthreads();  // c2s, ncl_s visible
    const float ncl = ncl_s;
    if (tid < NC) wsm[tid] = invs[tid] / (ncl * (float)NB);
    __syncthreads();  // wsm visible
    if (chunk == 0) {  // dist + reg terms, once per batch
        float acc = 0.f;
#pragma unroll
        for (int k = 0; k < 4; ++k) {
            int p = tid * 4 + k;
            int c = p >> 5, e = p & (NC - 1);
            if (c != e && reals[c] > 0.f && reals[e] > 0.f) {
                float cd = 0.f;
                for (int d2 = 0; d2 < 32; ++d2) {
                    float2 a = cT2[d2][c], bb = cT2[d2][e];
                    cd = fmaf(a.x, bb.x, cd);
                    cd = fmaf(a.y, bb.y, cd);
                }
                float cd2 = fmaxf(c2s[c] + c2s[e] - 2.f * cd, EPSF);
                float m = fmaxf(2.f - sqrtf(cd2), 0.f);
                acc += m * m;
            }
        }
        const float pairs = ncl * (ncl - 1.f) * 0.5f;
        acc = acc / (2.f * pairs * (float)NB);
        if (tid < NC) {  // delta_reg = sqrt(64) = 8
            float cn = sqrtf(fmaxf(c2s[tid], EPSF));
            float m = fmaxf(cn - 8.f, 0.f);
            acc += (m * m) / (ncl * (float)NB);
        }
#pragma unroll
        for (int o = 32; o >= 1; o >>= 1) acc += __shfl_xor(acc, o);
        if ((tid & 63) == 0) red[tid >> 6] = acc;
        __syncthreads();
        if (tid == 0) unsafeAtomicAdd(out, red[0] + red[1] + red[2] + red[3]);
    }
    // var term: per point, d2 = x2 + c2 - 2*dot (same expanded form + EPS as ref)
    const int cx = cv.x & 31, cy = cv.y & 31, cz = cv.z & 31, cw = cv.w & 31;
    const float* base = data + (size_t)b * ND * NN + n0;
    float dp0 = 0, dp1 = 0, dp2 = 0, dp3 = 0, q0 = 0, q1 = 0, q2 = 0, q3 = 0;
#pragma unroll 8
    for (int d2 = 0; d2 < 32; ++d2) {
        float4 xa = *(const float4*)(base + (size_t)(2 * d2) * NN);
        float4 xb = *(const float4*)(base + (size_t)(2 * d2 + 1) * NN);
        float2 ca = cT2[d2][cx], cb = cT2[d2][cy], cc = cT2[d2][cz], cd = cT2[d2][cw];
        dp0 = fmaf(xa.x, ca.x, dp0); dp0 = fmaf(xb.x, ca.y, dp0);
        dp1 = fmaf(xa.y, cb.x, dp1); dp1 = fmaf(xb.y, cb.y, dp1);
        dp2 = fmaf(xa.z, cc.x, dp2); dp2 = fmaf(xb.z, cc.y, dp2);
        dp3 = fmaf(xa.w, cd.x, dp3); dp3 = fmaf(xb.w, cd.y, dp3);
        q0 = fmaf(xa.x, xa.x, q0); q0 = fmaf(xb.x, xb.x, q0);
        q1 = fmaf(xa.y, xa.y, q1); q1 = fmaf(xb.y, xb.y, q1);
        q2 = fmaf(xa.z, xa.z, q2); q2 = fmaf(xb.z, xb.z, q2);
        q3 = fmaf(xa.w, xa.w, q3); q3 = fmaf(xb.w, xb.w, q3);
    }
    float t0 = fmaxf(q0 + c2s[cx] - 2.f * dp0, EPSF);
    float t1 = fmaxf(q1 + c2s[cy] - 2.f * dp1, EPSF);
    float t2 = fmaxf(q2 + c2s[cz] - 2.f * dp2, EPSF);
    float t3 = fmaxf(q3 + c2s[cw] - 2.f * dp3, EPSF);
    float e0 = fmaxf(sqrtf(t0) - 1.f, 0.f);
    float e1 = fmaxf(sqrtf(t1) - 1.f, 0.f);
    float e2 = fmaxf(sqrtf(t2) - 1.f, 0.f);
    float e3 = fmaxf(sqrtf(t3) - 1.f, 0.f);
    float acc = e0 * e0 * wsm[cx] + e1 * e1 * wsm[cy] + e2 * e2 * wsm[cz] + e3 * e3 * wsm[cw];
#pragma unroll
    for (int o = 32; o >= 1; o >>= 1) acc += __shfl_xor(acc, o);
    if ((tid & 63) == 0) red2[tid >> 6] = acc;
    __syncthreads();
    if (tid == 0) unsafeAtomicAdd(out, red2[0] + red2[1] + red2[2] + red2[3]);
}

extern "C" void kernel_launch(void* const* d_in, const int* in_sizes, int n_in,
                              void* d_out, int out_size, void* d_ws, size_t ws_size,
                              hipStream_t stream) {
    const float* data  = (const float*)d_in[0];
    const int* labels  = (const int*)d_in[1];
    float* out = (float*)d_out;
    float* ws  = (float*)d_ws;
    float* sums2   = ws;          // 32768 floats
    float* countsf = ws + 32768;  // 512 floats

    k_sums<<<dim3(ND + 1, NSPLIT, NB), 256, 0, stream>>>(data, labels, sums2, countsf, out);
    k_var<<<dim3(NN / 1024, NB), 256, 0, stream>>>(data, labels, sums2, countsf, out);
}